// Round 1
// baseline (1996.672 us; speedup 1.0000x reference)
//
#include <hip/hip_runtime.h>

#define NB 8
#define CC 256
#define TT 256
#define VV 25
#define BB (NB*VV)      // 200
#define NHH 8
#define O3 768
#define OP2 384         // O3/2 pair rows

typedef unsigned int u32;
typedef unsigned short u16;

__device__ __forceinline__ float blo(u32 u) { return __uint_as_float(u << 16); }
__device__ __forceinline__ float bhi(u32 u) { return __uint_as_float(u & 0xffff0000u); }
__device__ __forceinline__ u16 f2bf(float f) {
    u32 u = __float_as_uint(f);
    u += 0x7fffu + ((u >> 16) & 1u);
    return (u16)(u >> 16);
}
__device__ __forceinline__ u32 packbf(float lo, float hi) {
    return (u32)f2bf(lo) | ((u32)f2bf(hi) << 16);
}

// ---------------------------------------------------------------------------
// K1: x (N,C,T,V) f32  ->  xr[b=(n*V+v)][c][t] bf16   (coalesced both sides via LDS)
__global__ __launch_bounds__(256) void k_transpose_x(const float* __restrict__ x,
                                                     u16* __restrict__ xr) {
    __shared__ float tile[1600];
    const int tid = threadIdx.x;
    const int t0 = blockIdx.x * 64;
    const int c  = blockIdx.y;
    const int n  = blockIdx.z;
    size_t gbase = (((size_t)(n*CC + c))*TT + t0)*VV;
    for (int i = tid; i < 1600; i += 256) tile[i] = x[gbase + i];
    __syncthreads();
    for (int p = tid; p < 1600; p += 256) {
        int v = p >> 6, j = p & 63;
        xr[(((size_t)(n*VV + v))*CC + c)*TT + t0 + j] = f2bf(tile[j*VV + v]);
    }
}

// ---------------------------------------------------------------------------
// K1b: key_rel (511,32) f32 -> krp[d2][m] uint (bf16 pair: d=2*d2 low, 2*d2+1 high), m padded to 512
__global__ __launch_bounds__(256) void k_pack_krel(const float* __restrict__ kr,
                                                   u32* __restrict__ krp) {
    int g = blockIdx.x * 256 + threadIdx.x;     // 16*512 = 8192
    if (g >= 8192) return;
    int d2 = g >> 9, m = g & 511;
    u32 u = 0u;
    if (m < 511) u = packbf(kr[m*32 + 2*d2], kr[m*32 + 2*d2 + 1]);
    krp[g] = u;
}

// ---------------------------------------------------------------------------
// K2: qkv GEMM per b: O[o][t] = sum_c W[o][c]*xr[b][c][t] + bias[o]; q rows (o<256) scaled.
// Output pair-interleaved: qkvp[b][o2][t] uint = (bf16(o=2*o2), bf16(o=2*o2+1))
__global__ __launch_bounds__(256) void k_qkv_gemm(const float* __restrict__ W,
                                                  const float* __restrict__ bias,
                                                  const u16* __restrict__ xr,
                                                  u32* __restrict__ qkvp) {
    __shared__ __align__(16) float Wl[16][68];
    __shared__ __align__(16) float Xl[16][68];
    const int tid = threadIdx.x;
    const int t0 = blockIdx.x * 64;
    const int o0 = blockIdx.y * 64;
    const int b  = blockIdx.z;
    const int to = (tid >> 4) << 2;
    const int tc = (tid & 15) << 2;
    const u16* xb = xr + (size_t)b * CC * TT;
    float acc[4][4];
#pragma unroll
    for (int i = 0; i < 4; ++i)
#pragma unroll
        for (int j = 0; j < 4; ++j) acc[i][j] = 0.f;

    for (int c0 = 0; c0 < CC; c0 += 16) {
#pragma unroll
        for (int it = 0; it < 4; ++it) {
            int i = tid + it * 256;
            int kk = i & 15, oo = i >> 4;
            Wl[kk][oo] = W[(size_t)(o0 + oo) * CC + c0 + kk];
        }
#pragma unroll
        for (int it = 0; it < 4; ++it) {
            int i = tid + it * 256;
            int k = i >> 6, j = i & 63;
            Xl[k][j] = __uint_as_float((u32)xb[(size_t)(c0 + k) * TT + t0 + j] << 16);
        }
        __syncthreads();
#pragma unroll
        for (int k = 0; k < 16; ++k) {
            float4 av = *(const float4*)&Wl[k][to];
            float4 bv = *(const float4*)&Xl[k][tc];
            acc[0][0] += av.x*bv.x; acc[0][1] += av.x*bv.y; acc[0][2] += av.x*bv.z; acc[0][3] += av.x*bv.w;
            acc[1][0] += av.y*bv.x; acc[1][1] += av.y*bv.y; acc[1][2] += av.y*bv.z; acc[1][3] += av.y*bv.w;
            acc[2][0] += av.z*bv.x; acc[2][1] += av.z*bv.y; acc[2][2] += av.z*bv.z; acc[2][3] += av.z*bv.w;
            acc[3][0] += av.w*bv.x; acc[3][1] += av.w*bv.y; acc[3][2] += av.w*bv.z; acc[3][3] += av.w*bv.w;
        }
        __syncthreads();
    }
#pragma unroll
    for (int i = 0; i < 4; i += 2) {
        int oa = o0 + to + i;                    // even
        float ba = bias[oa], bb2 = bias[oa + 1];
        float sc = (oa < 256) ? 0.17677669529663687f : 1.0f;   // 1/sqrt(32) for q
        uint4 uu;
        uu.x = packbf((acc[i][0] + ba) * sc, (acc[i+1][0] + bb2) * sc);
        uu.y = packbf((acc[i][1] + ba) * sc, (acc[i+1][1] + bb2) * sc);
        uu.z = packbf((acc[i][2] + ba) * sc, (acc[i+1][2] + bb2) * sc);
        uu.w = packbf((acc[i][3] + ba) * sc, (acc[i+1][3] + bb2) * sc);
        *(uint4*)&qkvp[((size_t)b * OP2 + (oa >> 1)) * TT + t0 + tc] = uu;
    }
}

// ---------------------------------------------------------------------------
// K3: fused attention per (b,h). logits[t,s] = sum_d q[d,t]*(k[d,s] + key_rel[s-t+255, d]),
// softmax over s, attn[t,d] = sum_s w[t,s]*v[d,s]. Writes attn_buf[b][h*32+d][t] bf16.
__global__ __launch_bounds__(256) void k_attention(const u32* __restrict__ qkvp,
                                                   const u32* __restrict__ krp,
                                                   u16* __restrict__ attn) {
    __shared__ u32 Qp[16][256];
    __shared__ u32 Kp[16][256];
    __shared__ u32 KRp[16][512];
    __shared__ u32 Vp[16][257];                  // +1 pad: PV reads 16 rows at same s
    __shared__ __align__(4)  u16 Ol[32][258];    // +2 pad: row-parallel writes
    __shared__ __align__(16) float wbuf[4][2][256];

    const int tid = threadIdx.x;
    const int bh = blockIdx.x;
    const int b = bh >> 3, h = bh & 7;
    const u32* base = qkvp + (size_t)b * OP2 * TT;
    const u32* qg = base + (h * 16) * TT;
    const u32* kg = base + (128 + h * 16) * TT;
    const u32* vg = base + (256 + h * 16) * TT;

    for (int i = tid; i < 4096; i += 256) {
        int r = i >> 8, t = i & 255;
        Qp[r][t] = qg[i];
        Kp[r][t] = kg[i];
        Vp[r][t] = vg[i];
    }
    for (int i = tid; i < 8192; i += 256) ((u32*)KRp)[i] = krp[i];
    __syncthreads();

    const int wave = tid >> 6, lane = tid & 63;
    const int r = lane >> 5, d = lane & 31;

    for (int p = 0; p < 32; ++p) {
        const int t0r = wave * 64 + 2 * p;
        float inv0 = 0.f, inv1 = 0.f;
#pragma unroll
        for (int rr = 0; rr < 2; ++rr) {
            const int trow = t0r + rr;
            const int m0 = 255 - trow;
            float lg0 = 0.f, lg1 = 0.f, lg2 = 0.f, lg3 = 0.f;
#pragma unroll 4
            for (int d2 = 0; d2 < 16; ++d2) {
                u32 qv = Qp[d2][trow];
                float qlo = blo(qv), qhi = bhi(qv);
                u32 kv0 = Kp[d2][lane],       rv0 = KRp[d2][lane + m0];
                u32 kv1 = Kp[d2][lane + 64],  rv1 = KRp[d2][lane + 64 + m0];
                u32 kv2 = Kp[d2][lane + 128], rv2 = KRp[d2][lane + 128 + m0];
                u32 kv3 = Kp[d2][lane + 192], rv3 = KRp[d2][lane + 192 + m0];
                lg0 += qlo * (blo(kv0) + blo(rv0)) + qhi * (bhi(kv0) + bhi(rv0));
                lg1 += qlo * (blo(kv1) + blo(rv1)) + qhi * (bhi(kv1) + bhi(rv1));
                lg2 += qlo * (blo(kv2) + blo(rv2)) + qhi * (bhi(kv2) + bhi(rv2));
                lg3 += qlo * (blo(kv3) + blo(rv3)) + qhi * (bhi(kv3) + bhi(rv3));
            }
            float mx = fmaxf(fmaxf(lg0, lg1), fmaxf(lg2, lg3));
#pragma unroll
            for (int off = 32; off; off >>= 1) mx = fmaxf(mx, __shfl_xor(mx, off, 64));
            float e0 = __expf(lg0 - mx), e1 = __expf(lg1 - mx);
            float e2 = __expf(lg2 - mx), e3 = __expf(lg3 - mx);
            float sum = (e0 + e1) + (e2 + e3);
#pragma unroll
            for (int off = 32; off; off >>= 1) sum += __shfl_xor(sum, off, 64);
            float* wr = &wbuf[wave][rr][0];
            wr[lane] = e0; wr[lane + 64] = e1; wr[lane + 128] = e2; wr[lane + 192] = e3;
            if (rr == 0) inv0 = 1.f / sum; else inv1 = 1.f / sum;
        }
        // PV: lanes 0..31 -> row t0r (d=lane), lanes 32..63 -> row t0r+1
        const float* wr = r ? &wbuf[wave][1][0] : &wbuf[wave][0][0];
        const float inv = r ? inv1 : inv0;
        const int d2v = d >> 1;
        const bool odd = (d & 1);
        float a0 = 0.f, a1 = 0.f;
#pragma unroll 8
        for (int s = 0; s < 256; s += 2) {
            float2 wv = *(const float2*)(wr + s);
            u32 v0 = Vp[d2v][s];
            u32 v1 = Vp[d2v][s + 1];
            float f0 = odd ? bhi(v0) : blo(v0);
            float f1 = odd ? bhi(v1) : blo(v1);
            a0 = fmaf(wv.x, f0, a0);
            a1 = fmaf(wv.y, f1, a1);
        }
        Ol[d][t0r + r] = f2bf((a0 + a1) * inv);
    }
    __syncthreads();
    // coalesced writeback: attn_buf[b][h*32+d][t]
    u32* attn_u = (u32*)(attn + ((size_t)b * 256 + h * 32) * TT);
    for (int i = tid; i < 4096; i += 256) {
        int dd = i >> 7, tp = i & 127;
        u32 u = *(const u32*)&Ol[dd][2 * tp];
        attn_u[dd * 128 + tp] = u;
    }
}

// ---------------------------------------------------------------------------
// K4: out projection per b: y[o][t] = sum_c attn_w[o][c]*attn[b][c][t] + attn_b[o]  (bf16 out)
__global__ __launch_bounds__(256) void k_out_gemm(const float* __restrict__ W,
                                                  const float* __restrict__ bias,
                                                  const u16* __restrict__ attn,
                                                  u16* __restrict__ y) {
    __shared__ __align__(16) float Wl[16][68];
    __shared__ __align__(16) float Xl[16][68];
    const int tid = threadIdx.x;
    const int t0 = blockIdx.x * 64;
    const int o0 = blockIdx.y * 64;
    const int b  = blockIdx.z;
    const int to = (tid >> 4) << 2;
    const int tc = (tid & 15) << 2;
    const u16* xb = attn + (size_t)b * CC * TT;
    float acc[4][4];
#pragma unroll
    for (int i = 0; i < 4; ++i)
#pragma unroll
        for (int j = 0; j < 4; ++j) acc[i][j] = 0.f;

    for (int c0 = 0; c0 < CC; c0 += 16) {
#pragma unroll
        for (int it = 0; it < 4; ++it) {
            int i = tid + it * 256;
            int kk = i & 15, oo = i >> 4;
            Wl[kk][oo] = W[(size_t)(o0 + oo) * CC + c0 + kk];
        }
#pragma unroll
        for (int it = 0; it < 4; ++it) {
            int i = tid + it * 256;
            int k = i >> 6, j = i & 63;
            Xl[k][j] = __uint_as_float((u32)xb[(size_t)(c0 + k) * TT + t0 + j] << 16);
        }
        __syncthreads();
#pragma unroll
        for (int k = 0; k < 16; ++k) {
            float4 av = *(const float4*)&Wl[k][to];
            float4 bv = *(const float4*)&Xl[k][tc];
            acc[0][0] += av.x*bv.x; acc[0][1] += av.x*bv.y; acc[0][2] += av.x*bv.z; acc[0][3] += av.x*bv.w;
            acc[1][0] += av.y*bv.x; acc[1][1] += av.y*bv.y; acc[1][2] += av.y*bv.z; acc[1][3] += av.y*bv.w;
            acc[2][0] += av.z*bv.x; acc[2][1] += av.z*bv.y; acc[2][2] += av.z*bv.z; acc[2][3] += av.z*bv.w;
            acc[3][0] += av.w*bv.x; acc[3][1] += av.w*bv.y; acc[3][2] += av.w*bv.z; acc[3][3] += av.w*bv.w;
        }
        __syncthreads();
    }
#pragma unroll
    for (int i = 0; i < 4; ++i) {
        int o = o0 + to + i;
        float bb2 = bias[o];
        ushort4 s4;
        s4.x = f2bf(acc[i][0] + bb2);
        s4.y = f2bf(acc[i][1] + bb2);
        s4.z = f2bf(acc[i][2] + bb2);
        s4.w = f2bf(acc[i][3] + bb2);
        *(ushort4*)&y[((size_t)b * CC + o) * TT + t0 + tc] = s4;
    }
}

// ---------------------------------------------------------------------------
// K5: out[n][o][t][v] = relu((y[(n*V+v)][o][t] + x[n][o][t][v]) * inv[o] + shift[o])
__global__ __launch_bounds__(256) void k_final(const u16* __restrict__ y,
                                               const float* __restrict__ x,
                                               const float* __restrict__ gamma,
                                               const float* __restrict__ beta,
                                               const float* __restrict__ mean,
                                               const float* __restrict__ var,
                                               float* __restrict__ out) {
    __shared__ float tile[1600];
    const int tid = threadIdx.x;
    const int t0 = blockIdx.x * 64;
    const int o  = blockIdx.y;
    const int n  = blockIdx.z;
    float inv = gamma[o] * rsqrtf(var[o] + 1e-5f);
    float sh  = beta[o] - mean[o] * inv;
    for (int p = tid; p < 1600; p += 256) {
        int v = p >> 6, j = p & 63;
        tile[j * VV + v] = __uint_as_float(
            (u32)y[(((size_t)(n*VV + v))*CC + o)*TT + t0 + j] << 16);
    }
    __syncthreads();
    size_t gbase = (((size_t)(n*CC + o))*TT + t0)*VV;
    for (int i = tid; i < 1600; i += 256) {
        float val = tile[i] + x[gbase + i];
        val = val * inv + sh;
        out[gbase + i] = fmaxf(val, 0.f);
    }
}

// ---------------------------------------------------------------------------
extern "C" void kernel_launch(void* const* d_in, const int* in_sizes, int n_in,
                              void* d_out, int out_size, void* d_ws, size_t ws_size,
                              hipStream_t stream) {
    const float* x        = (const float*)d_in[0];
    const float* qkv_w    = (const float*)d_in[1];
    const float* qkv_b    = (const float*)d_in[2];
    const float* key_rel  = (const float*)d_in[3];
    const float* attn_w   = (const float*)d_in[4];
    const float* attn_b   = (const float*)d_in[5];
    const float* bn_gamma = (const float*)d_in[6];
    const float* bn_beta  = (const float*)d_in[7];
    const float* bn_mean  = (const float*)d_in[8];
    const float* bn_var   = (const float*)d_in[9];
    float* out = (float*)d_out;

    char* ws = (char*)d_ws;
    // layout: qkvp (78,643,200) | krp (32,768) | attn (26,214,400) | xr/y (26,214,400)
    u32* qkvp   = (u32*)ws;
    u32* krp    = (u32*)(ws + 78643200);
    u16* attnb  = (u16*)(ws + 78675968);
    u16* xr     = (u16*)(ws + 104890368);
    u16* y      = xr;   // xr dead after k_qkv_gemm; reuse for y

    k_transpose_x<<<dim3(4, 256, 8), 256, 0, stream>>>(x, xr);
    k_pack_krel<<<32, 256, 0, stream>>>(key_rel, krp);
    k_qkv_gemm<<<dim3(4, 12, 200), 256, 0, stream>>>(qkv_w, qkv_b, xr, qkvp);
    k_attention<<<1600, 256, 0, stream>>>(qkvp, krp, attnb);
    k_out_gemm<<<dim3(4, 4, 200), 256, 0, stream>>>(attn_w, attn_b, attnb, y);
    k_final<<<dim3(4, 256, 8), 256, 0, stream>>>(y, x, bn_gamma, bn_beta, bn_mean, bn_var, out);
}

// Round 2
// 710.259 us; speedup vs baseline: 2.8112x; 2.8112x over previous
//
#include <hip/hip_runtime.h>

#define NB 8
#define CC 256
#define TT 256
#define VV 25
#define O3 768

typedef unsigned int u32;
typedef unsigned short u16;
typedef __attribute__((ext_vector_type(8))) short s16x8;
typedef __attribute__((ext_vector_type(4))) float f32x4;

__device__ __forceinline__ float bf2f(u16 u) { return __uint_as_float((u32)u << 16); }
__device__ __forceinline__ u16 f2bf(float f) {
    u32 u = __float_as_uint(f);
    u += 0x7fffu + ((u >> 16) & 1u);
    return (u16)(u >> 16);
}

// ---------------------------------------------------------------------------
// K1: x (N,C,T,V) f32  ->  xr[b=(n*V+v)][c][t] bf16
__global__ __launch_bounds__(256) void k_transpose_x(const float* __restrict__ x,
                                                     u16* __restrict__ xr) {
    __shared__ float tile[1600];
    const int tid = threadIdx.x;
    const int t0 = blockIdx.x * 64;
    const int c  = blockIdx.y;
    const int n  = blockIdx.z;
    size_t gbase = (((size_t)(n*CC + c))*TT + t0)*VV;
    for (int i = tid; i < 1600; i += 256) tile[i] = x[gbase + i];
    __syncthreads();
    for (int p = tid; p < 1600; p += 256) {
        int v = p >> 6, j = p & 63;
        xr[(((size_t)(n*VV + v))*CC + c)*TT + t0 + j] = f2bf(tile[j*VV + v]);
    }
}

// ---------------------------------------------------------------------------
// K1b: key_rel (511,32) f32 -> krb[m][d] bf16, 512 rows (row 511 zeroed)
__global__ __launch_bounds__(256) void k_pack_krel(const float* __restrict__ kr,
                                                   u16* __restrict__ krb) {
    int g = blockIdx.x * 256 + threadIdx.x;     // 64*256 = 16384
    if (g >= 16384) return;
    krb[g] = (g < 511*32) ? f2bf(kr[g]) : (u16)0;
}

// ---------------------------------------------------------------------------
// K2: qkv GEMM per b. Outputs in MFMA-friendly layouts:
//   qb[b][h][t][d] (scaled by 1/sqrt(32)), kb[b][h][s][d], vb[b][h][d][t]  (bf16)
__global__ __launch_bounds__(256) void k_qkv_gemm(const float* __restrict__ W,
                                                  const float* __restrict__ bias,
                                                  const u16* __restrict__ xr,
                                                  u16* __restrict__ qb,
                                                  u16* __restrict__ kb,
                                                  u16* __restrict__ vb) {
    __shared__ __align__(16) float Wl[16][68];
    __shared__ __align__(16) float Xl[16][68];
    __shared__ __align__(16) u16 St[64*80];
    const int tid = threadIdx.x;
    const int t0 = blockIdx.x * 64;
    const int o0 = blockIdx.y * 64;
    const int b  = blockIdx.z;
    const int to = (tid >> 4) << 2;
    const int tc = (tid & 15) << 2;
    const u16* xb = xr + (size_t)b * CC * TT;
    float acc[4][4];
#pragma unroll
    for (int i = 0; i < 4; ++i)
#pragma unroll
        for (int j = 0; j < 4; ++j) acc[i][j] = 0.f;

    for (int c0 = 0; c0 < CC; c0 += 16) {
#pragma unroll
        for (int it = 0; it < 4; ++it) {
            int i = tid + it * 256;
            int kk = i & 15, oo = i >> 4;
            Wl[kk][oo] = W[(size_t)(o0 + oo) * CC + c0 + kk];
        }
#pragma unroll
        for (int it = 0; it < 4; ++it) {
            int i = tid + it * 256;
            int k = i >> 6, j = i & 63;
            Xl[k][j] = bf2f(xb[(size_t)(c0 + k) * TT + t0 + j]);
        }
        __syncthreads();
#pragma unroll
        for (int k = 0; k < 16; ++k) {
            float4 av = *(const float4*)&Wl[k][to];
            float4 bv = *(const float4*)&Xl[k][tc];
            acc[0][0] += av.x*bv.x; acc[0][1] += av.x*bv.y; acc[0][2] += av.x*bv.z; acc[0][3] += av.x*bv.w;
            acc[1][0] += av.y*bv.x; acc[1][1] += av.y*bv.y; acc[1][2] += av.y*bv.z; acc[1][3] += av.y*bv.w;
            acc[2][0] += av.z*bv.x; acc[2][1] += av.z*bv.y; acc[2][2] += av.z*bv.z; acc[2][3] += av.z*bv.w;
            acc[3][0] += av.w*bv.x; acc[3][1] += av.w*bv.y; acc[3][2] += av.w*bv.z; acc[3][3] += av.w*bv.w;
        }
        __syncthreads();
    }

    if (o0 >= 512) {
        // V rows: vb[b][h][d][t] == [o][t] order -> direct coalesced write
#pragma unroll
        for (int i = 0; i < 4; ++i) {
            int o = o0 + to + i;
            float bb2 = bias[o];
            int orel = o - 512;
            int hh = orel >> 5, dd = orel & 31;
            ushort4 s4;
            s4.x = f2bf(acc[i][0] + bb2);
            s4.y = f2bf(acc[i][1] + bb2);
            s4.z = f2bf(acc[i][2] + bb2);
            s4.w = f2bf(acc[i][3] + bb2);
            *(ushort4*)&vb[(((size_t)(b*8 + hh))*32 + dd)*TT + t0 + tc] = s4;
        }
    } else {
        // Q/K rows: transpose to [t][d] via LDS
        const float sc = (o0 < 256) ? 0.17677669529663687f : 1.0f;   // 1/sqrt(32) for q
        u16* dstbase = (o0 < 256) ? qb : kb;
        const int o0rel = (o0 < 256) ? o0 : (o0 - 256);
#pragma unroll
        for (int i = 0; i < 4; ++i) {
            int o = o0 + to + i;
            float bb2 = bias[o];
#pragma unroll
            for (int j = 0; j < 4; ++j)
                St[(tc + j)*80 + to + i] = f2bf((acc[i][j] + bb2) * sc);
        }
        __syncthreads();
        int t_l = tid >> 2, seg = tid & 3;
        int hh = (o0rel >> 5) + (seg >> 1);
        int d0 = (seg & 1) * 16;
        uint4 u0 = *(const uint4*)&St[t_l*80 + seg*16];
        uint4 u1 = *(const uint4*)&St[t_l*80 + seg*16 + 8];
        u16* dst = dstbase + (((size_t)(b*8 + hh))*TT + t0 + t_l)*32 + d0;
        *(uint4*)dst = u0;
        *(uint4*)&dst[8] = u1;
    }
}

// ---------------------------------------------------------------------------
// K3: MFMA attention. Block = (b,h,t-tile of 32). 4 waves.
//   phase1: R[tl][ml] = Q x KR^T over rel band (287 wide)
//   phase2: S = Q x K^T, += gathered R (rel_to_abs fold), softmax (cross-wave)
//   phase3: O = P x V^T -> attn[b][h*32+d][t] bf16
__global__ __launch_bounds__(256) void k_attention_mfma(const u16* __restrict__ qb,
                                                        const u16* __restrict__ kb,
                                                        const u16* __restrict__ vb,
                                                        const u16* __restrict__ krb,
                                                        u16* __restrict__ attn) {
    __shared__ __align__(16) u16 Klds[256*40];     // [s][d] stride 40
    __shared__ __align__(16) u16 Vlds[32*264];     // [d][s] stride 264
    __shared__ __align__(16) u16 KRlds[288*40];    // [ml][d] stride 40
    __shared__ __align__(16) u16 RPlds[32*290];    // R: [tl][ml] stride 290; reused as P: [tl][s] stride 264
    __shared__ float smax[2][2][16];
    __shared__ float ssum[2][2][16];

    const int tid = threadIdx.x;
    const int t0 = blockIdx.x * 32;
    const int bh = blockIdx.y;
    const int b = bh >> 3, h = bh & 7;
    const int m_base = 224 - t0;                   // band start; ml = s - tl + 31

    const u16* kg  = kb  + (size_t)bh * 8192;
    const u16* vg  = vb  + (size_t)bh * 8192;
    const u16* krg = krb + m_base * 32;

    for (int i = tid; i < 1024; i += 256) {        // K: 256 rows x 4 x uint4
        int s = i >> 2, c = i & 3;
        *(uint4*)&Klds[s*40 + c*8] = ((const uint4*)kg)[i];
    }
    for (int i = tid; i < 1024; i += 256) {        // V: 32 rows x 32 x uint4
        int d = i >> 5, c = i & 31;
        *(uint4*)&Vlds[d*264 + c*8] = ((const uint4*)vg)[i];
    }
    for (int i = tid; i < 1152; i += 256) {        // KR: 288 rows x 4 x uint4
        int m = i >> 2, c = i & 3;
        *(uint4*)&KRlds[m*40 + c*8] = ((const uint4*)krg)[i];
    }

    const int wave = tid >> 6, lane = tid & 63;
    const int quad = lane >> 4, l15 = lane & 15;
    const int g = wave >> 1, half = wave & 1;      // g: row-group (16 rows), half: s/n split

    // A fragment: Q[t = t0+16g+l15][k = quad*8+j] straight from global (coalesced)
    s16x8 afrag = *(const s16x8*)(qb + (((size_t)bh*TT) + t0 + 16*g + l15)*32 + quad*8);

    __syncthreads();

    // ---- phase 1: rel GEMM, 18 n-tiles split 9/9 between the two waves of group g
    for (int nn = 0; nn < 9; ++nn) {
        int m0 = (half * 9 + nn) * 16;
        s16x8 bfrag = *(const s16x8*)&KRlds[(m0 + l15)*40 + quad*8];
        f32x4 c = {0.f, 0.f, 0.f, 0.f};
        c = __builtin_amdgcn_mfma_f32_16x16x32_bf16(afrag, bfrag, c, 0, 0, 0);
        int tl = 16*g + quad*4;
        int mcol = m0 + l15;
        RPlds[(tl+0)*290 + mcol] = f2bf(c[0]);
        RPlds[(tl+1)*290 + mcol] = f2bf(c[1]);
        RPlds[(tl+2)*290 + mcol] = f2bf(c[2]);
        RPlds[(tl+3)*290 + mcol] = f2bf(c[3]);
    }
    __syncthreads();

    // ---- phase 2: S = Q K^T over this wave's s-half (8 tiles)
    f32x4 acc[8];
#pragma unroll
    for (int n = 0; n < 8; ++n) {
        int s0 = half*128 + n*16;
        s16x8 bfrag = *(const s16x8*)&Klds[(s0 + l15)*40 + quad*8];
        f32x4 z = {0.f, 0.f, 0.f, 0.f};
        acc[n] = __builtin_amdgcn_mfma_f32_16x16x32_bf16(afrag, bfrag, z, 0, 0, 0);
    }
    // rel gather-add: S[t][s] += R[tl][s - tl + 31]
#pragma unroll
    for (int n = 0; n < 8; ++n) {
        int s = half*128 + n*16 + l15;
#pragma unroll
        for (int r = 0; r < 4; ++r) {
            int tl = 16*g + quad*4 + r;
            acc[n][r] += bf2f(RPlds[tl*290 + (s - tl + 31)]);
        }
    }
    // softmax (rows live across the 16 lanes of each quad + the partner wave)
    float pm[4];
#pragma unroll
    for (int r = 0; r < 4; ++r) {
        float m = acc[0][r];
#pragma unroll
        for (int n = 1; n < 8; ++n) m = fmaxf(m, acc[n][r]);
#pragma unroll
        for (int off = 1; off < 16; off <<= 1) m = fmaxf(m, __shfl_xor(m, off, 64));
        pm[r] = m;
    }
    if (l15 == 0) {
#pragma unroll
        for (int r = 0; r < 4; ++r) smax[g][half][quad*4 + r] = pm[r];
    }
    __syncthreads();
    float psum[4];
#pragma unroll
    for (int r = 0; r < 4; ++r) {
        float m = fmaxf(pm[r], smax[g][1 - half][quad*4 + r]);
        float s = 0.f;
#pragma unroll
        for (int n = 0; n < 8; ++n) {
            float e = __expf(acc[n][r] - m);
            acc[n][r] = e;
            s += e;
        }
#pragma unroll
        for (int off = 1; off < 16; off <<= 1) s += __shfl_xor(s, off, 64);
        psum[r] = s;
    }
    if (l15 == 0) {
#pragma unroll
        for (int r = 0; r < 4; ++r) ssum[g][half][quad*4 + r] = psum[r];
    }
    __syncthreads();
    float invr[4];
#pragma unroll
    for (int r = 0; r < 4; ++r)
        invr[r] = 1.f / (psum[r] + ssum[g][1 - half][quad*4 + r]);
    // write P (reuses R region; all gathers completed before first sync)
#pragma unroll
    for (int n = 0; n < 8; ++n) {
        int s = half*128 + n*16 + l15;
#pragma unroll
        for (int r = 0; r < 4; ++r) {
            int tl = 16*g + quad*4 + r;
            RPlds[tl*264 + s] = f2bf(acc[n][r] * invr[r]);
        }
    }
    __syncthreads();

    // ---- phase 3: O = P V^T. Wave: rows 16g, d-range 16*half.
    f32x4 o = {0.f, 0.f, 0.f, 0.f};
#pragma unroll
    for (int ks = 0; ks < 8; ++ks) {
        s16x8 a  = *(const s16x8*)&RPlds[(16*g + l15)*264 + ks*32 + quad*8];
        s16x8 bv = *(const s16x8*)&Vlds[(half*16 + l15)*264 + ks*32 + quad*8];
        o = __builtin_amdgcn_mfma_f32_16x16x32_bf16(a, bv, o, 0, 0, 0);
    }
    int d = half*16 + l15;
    int t = t0 + 16*g + quad*4;
    ushort4 s4;
    s4.x = f2bf(o[0]); s4.y = f2bf(o[1]); s4.z = f2bf(o[2]); s4.w = f2bf(o[3]);
    *(ushort4*)&attn[(((size_t)b*CC) + h*32 + d)*TT + t] = s4;
}

// ---------------------------------------------------------------------------
// K4: out projection per b: y[o][t] = sum_c attn_w[o][c]*attn[b][c][t] + attn_b[o]
__global__ __launch_bounds__(256) void k_out_gemm(const float* __restrict__ W,
                                                  const float* __restrict__ bias,
                                                  const u16* __restrict__ attn,
                                                  u16* __restrict__ y) {
    __shared__ __align__(16) float Wl[16][68];
    __shared__ __align__(16) float Xl[16][68];
    const int tid = threadIdx.x;
    const int t0 = blockIdx.x * 64;
    const int o0 = blockIdx.y * 64;
    const int b  = blockIdx.z;
    const int to = (tid >> 4) << 2;
    const int tc = (tid & 15) << 2;
    const u16* xb = attn + (size_t)b * CC * TT;
    float acc[4][4];
#pragma unroll
    for (int i = 0; i < 4; ++i)
#pragma unroll
        for (int j = 0; j < 4; ++j) acc[i][j] = 0.f;

    for (int c0 = 0; c0 < CC; c0 += 16) {
#pragma unroll
        for (int it = 0; it < 4; ++it) {
            int i = tid + it * 256;
            int kk = i & 15, oo = i >> 4;
            Wl[kk][oo] = W[(size_t)(o0 + oo) * CC + c0 + kk];
        }
#pragma unroll
        for (int it = 0; it < 4; ++it) {
            int i = tid + it * 256;
            int k = i >> 6, j = i & 63;
            Xl[k][j] = bf2f(xb[(size_t)(c0 + k) * TT + t0 + j]);
        }
        __syncthreads();
#pragma unroll
        for (int k = 0; k < 16; ++k) {
            float4 av = *(const float4*)&Wl[k][to];
            float4 bv = *(const float4*)&Xl[k][tc];
            acc[0][0] += av.x*bv.x; acc[0][1] += av.x*bv.y; acc[0][2] += av.x*bv.z; acc[0][3] += av.x*bv.w;
            acc[1][0] += av.y*bv.x; acc[1][1] += av.y*bv.y; acc[1][2] += av.y*bv.z; acc[1][3] += av.y*bv.w;
            acc[2][0] += av.z*bv.x; acc[2][1] += av.z*bv.y; acc[2][2] += av.z*bv.z; acc[2][3] += av.z*bv.w;
            acc[3][0] += av.w*bv.x; acc[3][1] += av.w*bv.y; acc[3][2] += av.w*bv.z; acc[3][3] += av.w*bv.w;
        }
        __syncthreads();
    }
#pragma unroll
    for (int i = 0; i < 4; ++i) {
        int o = o0 + to + i;
        float bb2 = bias[o];
        ushort4 s4;
        s4.x = f2bf(acc[i][0] + bb2);
        s4.y = f2bf(acc[i][1] + bb2);
        s4.z = f2bf(acc[i][2] + bb2);
        s4.w = f2bf(acc[i][3] + bb2);
        *(ushort4*)&y[((size_t)b * CC + o) * TT + t0 + tc] = s4;
    }
}

// ---------------------------------------------------------------------------
// K5: out[n][o][t][v] = relu((y[(n*V+v)][o][t] + x[n][o][t][v]) * inv[o] + shift[o])
__global__ __launch_bounds__(256) void k_final(const u16* __restrict__ y,
                                               const float* __restrict__ x,
                                               const float* __restrict__ gamma,
                                               const float* __restrict__ beta,
                                               const float* __restrict__ mean,
                                               const float* __restrict__ var,
                                               float* __restrict__ out) {
    __shared__ float tile[1600];
    const int tid = threadIdx.x;
    const int t0 = blockIdx.x * 64;
    const int o  = blockIdx.y;
    const int n  = blockIdx.z;
    float inv = gamma[o] * rsqrtf(var[o] + 1e-5f);
    float sh  = beta[o] - mean[o] * inv;
    for (int p = tid; p < 1600; p += 256) {
        int v = p >> 6, j = p & 63;
        tile[j * VV + v] = bf2f(y[(((size_t)(n*VV + v))*CC + o)*TT + t0 + j]);
    }
    __syncthreads();
    size_t gbase = (((size_t)(n*CC + o))*TT + t0)*VV;
    for (int i = tid; i < 1600; i += 256) {
        float val = tile[i] + x[gbase + i];
        val = val * inv + sh;
        out[gbase + i] = fmaxf(val, 0.f);
    }
}

// ---------------------------------------------------------------------------
extern "C" void kernel_launch(void* const* d_in, const int* in_sizes, int n_in,
                              void* d_out, int out_size, void* d_ws, size_t ws_size,
                              hipStream_t stream) {
    const float* x        = (const float*)d_in[0];
    const float* qkv_w    = (const float*)d_in[1];
    const float* qkv_b    = (const float*)d_in[2];
    const float* key_rel  = (const float*)d_in[3];
    const float* attn_w   = (const float*)d_in[4];
    const float* attn_b   = (const float*)d_in[5];
    const float* bn_gamma = (const float*)d_in[6];
    const float* bn_beta  = (const float*)d_in[7];
    const float* bn_mean  = (const float*)d_in[8];
    const float* bn_var   = (const float*)d_in[9];
    float* out = (float*)d_out;

    char* ws = (char*)d_ws;
    // layout (bytes): qb 26,214,400 | kb 26,214,400 | vb 26,214,400 | attn 26,214,400
    //                 | xr/y 26,214,400 | krb 32,768  = 131,104,768 total
    u16* qb    = (u16*)ws;
    u16* kb    = (u16*)(ws + 26214400);
    u16* vb    = (u16*)(ws + 52428800);
    u16* attnb = (u16*)(ws + 78643200);
    u16* xr    = (u16*)(ws + 104857600);
    u16* krb   = (u16*)(ws + 131072000);
    u16* y     = xr;   // xr dead after k_qkv_gemm; reuse for y

    k_transpose_x<<<dim3(4, 256, 8), 256, 0, stream>>>(x, xr);
    k_pack_krel<<<64, 256, 0, stream>>>(key_rel, krb);
    k_qkv_gemm<<<dim3(4, 12, 200), 256, 0, stream>>>(qkv_w, qkv_b, xr, qb, kb, vb);
    k_attention_mfma<<<dim3(8, 1600), 256, 0, stream>>>(qb, kb, vb, krb, attnb);
    k_out_gemm<<<dim3(4, 4, 200), 256, 0, stream>>>(attn_w, attn_b, attnb, y);
    k_final<<<dim3(4, 256, 8), 256, 0, stream>>>(y, x, bn_gamma, bn_beta, bn_mean, bn_var, out);
}

// Round 3
// 430.430 us; speedup vs baseline: 4.6388x; 1.6501x over previous
//
#include <hip/hip_runtime.h>

#define NB 8
#define CC 256
#define TT 256
#define VV 25

typedef unsigned int u32;
typedef unsigned short u16;
typedef __attribute__((ext_vector_type(8))) short s16x8;
typedef __attribute__((ext_vector_type(4))) float f32x4;

__device__ __forceinline__ float bf2f(u16 u) { return __uint_as_float((u32)u << 16); }
__device__ __forceinline__ u16 f2bf(float f) {
    u32 u = __float_as_uint(f);
    u += 0x7fffu + ((u >> 16) & 1u);
    return (u16)(u >> 16);
}

__device__ __forceinline__ void gload_lds16(const void* g, void* l) {
    __builtin_amdgcn_global_load_lds(
        (const __attribute__((address_space(1))) u32*)g,
        (__attribute__((address_space(3))) u32*)l, 16, 0, 0);
}

// ---------------------------------------------------------------------------
// K1: x (N,C,T,V) f32 -> xT[b=(n*V+v)][t][c] bf16  (k-contiguous rows for MFMA A/B)
__global__ __launch_bounds__(256) void k_transpose_x(const float* __restrict__ x,
                                                     u16* __restrict__ xT) {
    __shared__ u16 L[25 * 32 * 34];
    const int tid = threadIdx.x;
    const int c0 = blockIdx.x * 32;
    const int t0 = blockIdx.y * 32;
    const int n  = blockIdx.z;
    for (int i = tid; i < 25600; i += 256) {
        int ci = i / 800;
        int rem = i - ci * 800;
        int t = rem / 25;
        int v = rem - t * 25;
        float f = x[(((size_t)(n * CC + c0 + ci)) * TT + t0) * VV + rem];
        L[(v * 32 + t) * 34 + ci] = f2bf(f);
    }
    __syncthreads();
    for (int i = tid; i < 12800; i += 256) {
        int row = i >> 4, cp = i & 15;
        int v = row >> 5, t = row & 31;
        u32 val = *(const u32*)&L[row * 34 + cp * 2];
        *(u32*)&xT[(((size_t)(n * VV + v)) * TT + t0 + t) * CC + c0 + cp * 2] = val;
    }
}

// ---------------------------------------------------------------------------
// K1b: key_rel (511,32) f32 -> krb[m][d] bf16, 512 rows (row 511 zeroed)
__global__ __launch_bounds__(256) void k_pack_krel(const float* __restrict__ kr,
                                                   u16* __restrict__ krb) {
    int g = blockIdx.x * 256 + threadIdx.x;
    if (g >= 16384) return;
    krb[g] = (g < 511 * 32) ? f2bf(kr[g]) : (u16)0;
}

// ---------------------------------------------------------------------------
// K1c: pack weights to bf16 (q rows pre-scaled by 1/sqrt(32)), scaled q bias
__global__ __launch_bounds__(256) void k_pack_w(const float* __restrict__ qkv_w,
                                                const float* __restrict__ attn_w,
                                                const float* __restrict__ qkv_b,
                                                u16* __restrict__ Wqk,
                                                u16* __restrict__ Wv,
                                                u16* __restrict__ Wo,
                                                float* __restrict__ bqk) {
    const float s = 0.17677669529663687f;
    int g = blockIdx.x * 256 + threadIdx.x;
    if (g < 131072) {
        Wqk[g] = f2bf(qkv_w[g] * (g < 65536 ? s : 1.f));
    } else if (g < 196608) {
        Wv[g - 131072] = f2bf(qkv_w[g]);             // qkv_w rows 512..767
    } else if (g < 262144) {
        Wo[g - 196608] = f2bf(attn_w[g - 196608]);
    } else if (g < 262656) {
        int i = g - 262144;
        bqk[i] = qkv_b[i] * (i < 256 ? s : 1.f);
    }
}

// ---------------------------------------------------------------------------
// m97-style mainloop: 128x128 tile, BK=32, async global->LDS, 4 waves x (4x4) 16x16 tiles.
// A rows = C-rows (m), B rows = C-cols (n); both k-contiguous with stride 256.
__device__ __forceinline__ void gemm_mainloop(const u16* __restrict__ Arow,
                                              const u16* __restrict__ Brow,
                                              u16* At, u16* Bt,
                                              int wave, int lane, f32x4 acc[4][4]) {
    const int srow = lane >> 2, scol = (lane & 3) * 8;
    const int quad = lane >> 4, l15 = lane & 15;
    for (int k0 = 0; k0 < 256; k0 += 32) {
#pragma unroll
        for (int it = 0; it < 2; ++it) {
            int ch = it * 4 + wave;
            gload_lds16(Arow + (size_t)(ch * 16 + srow) * 256 + k0 + scol, At + ch * 512 + lane * 8);
            gload_lds16(Brow + (size_t)(ch * 16 + srow) * 256 + k0 + scol, Bt + ch * 512 + lane * 8);
        }
        __syncthreads();
        s16x8 af[4], bfr[4];
#pragma unroll
        for (int i = 0; i < 4; ++i)
            af[i] = *(const s16x8*)&At[((wave & 1) * 64 + i * 16 + l15) * 32 + quad * 8];
#pragma unroll
        for (int j = 0; j < 4; ++j)
            bfr[j] = *(const s16x8*)&Bt[((wave >> 1) * 64 + j * 16 + l15) * 32 + quad * 8];
#pragma unroll
        for (int i = 0; i < 4; ++i)
#pragma unroll
            for (int j = 0; j < 4; ++j)
                acc[i][j] = __builtin_amdgcn_mfma_f32_16x16x32_bf16(af[i], bfr[j], acc[i][j], 0, 0, 0);
        __syncthreads();
    }
}

// ---------------------------------------------------------------------------
// K2a: C[t][o] = xT . Wqk^T + bqk  -> qT[b][h][t][32], kT[b][h][s][32]
__global__ __launch_bounds__(256) void k_gemm_qk(const u16* __restrict__ xT,
                                                 const u16* __restrict__ Wqk,
                                                 const float* __restrict__ bqk,
                                                 u16* __restrict__ qT,
                                                 u16* __restrict__ kT) {
    __shared__ __align__(16) u16 At[128 * 32];
    __shared__ __align__(16) u16 Bt[128 * 32];
    const int tid = threadIdx.x, wave = tid >> 6, lane = tid & 63;
    const int quad = lane >> 4, l15 = lane & 15;
    const int n0 = blockIdx.x * 128;     // o
    const int m0 = blockIdx.y * 128;     // t
    const int b  = blockIdx.z;
    const u16* Arow = xT + (size_t)b * 65536 + (size_t)m0 * 256;
    const u16* Brow = Wqk + (size_t)n0 * 256;
    f32x4 acc[4][4];
#pragma unroll
    for (int i = 0; i < 4; ++i)
#pragma unroll
        for (int j = 0; j < 4; ++j) acc[i][j] = (f32x4){0.f, 0.f, 0.f, 0.f};
    gemm_mainloop(Arow, Brow, At, Bt, wave, lane, acc);

    const bool isq = (n0 < 256);
    u16* base = isq ? qT : kT;
    const int on0 = (isq ? n0 : n0 - 256) + (wave >> 1) * 64;
#pragma unroll
    for (int j = 0; j < 4; ++j) {
        int o = on0 + j * 16 + l15;
        float bias = bqk[(isq ? 0 : 256) + o];
        u16* dcol = base + (size_t)(b * 8 + (o >> 5)) * 8192 + (o & 31);
#pragma unroll
        for (int i = 0; i < 4; ++i) {
            int tbase = m0 + (wave & 1) * 64 + i * 16 + quad * 4;
#pragma unroll
            for (int r = 0; r < 4; ++r)
                dcol[(size_t)(tbase + r) * 32] = f2bf(acc[i][j][r] + bias);
        }
    }
}

// ---------------------------------------------------------------------------
// K2b (used twice): C[o][t] = W . Bsrc^T + bias -> Out[b][o][t]
//   V:   W=Wv, Bsrc=xT,    Out=vb  (== vb[b][h][d][t])
//   OUT: W=Wo, Bsrc=attnT, Out=y
__global__ __launch_bounds__(256) void k_gemm_av(const u16* __restrict__ Wb,
                                                 const float* __restrict__ bias,
                                                 const u16* __restrict__ Bsrc,
                                                 u16* __restrict__ Out) {
    __shared__ __align__(16) u16 At[128 * 32];
    __shared__ __align__(16) u16 Bt[128 * 32];
    const int tid = threadIdx.x, wave = tid >> 6, lane = tid & 63;
    const int quad = lane >> 4, l15 = lane & 15;
    const int n0 = blockIdx.x * 128;     // t
    const int m0 = blockIdx.y * 128;     // o
    const int b  = blockIdx.z;
    const u16* Arow = Wb + (size_t)m0 * 256;
    const u16* Brow = Bsrc + (size_t)b * 65536 + (size_t)n0 * 256;
    f32x4 acc[4][4];
#pragma unroll
    for (int i = 0; i < 4; ++i)
#pragma unroll
        for (int j = 0; j < 4; ++j) acc[i][j] = (f32x4){0.f, 0.f, 0.f, 0.f};
    gemm_mainloop(Arow, Brow, At, Bt, wave, lane, acc);

    u16* ob = Out + (size_t)b * 65536;
    const int nb = n0 + (wave >> 1) * 64 + l15;
#pragma unroll
    for (int i = 0; i < 4; ++i) {
        int o_i = m0 + (wave & 1) * 64 + i * 16 + quad * 4;
#pragma unroll
        for (int r = 0; r < 4; ++r) {
            float bv = bias[o_i + r];
            u16* orow = ob + (size_t)(o_i + r) * 256 + nb;
#pragma unroll
            for (int j = 0; j < 4; ++j)
                orow[j * 16] = f2bf(acc[i][j][r] + bv);
        }
    }
}

// ---------------------------------------------------------------------------
// K3: MFMA attention (unchanged core). Output now attnT[b][t][c=h*32+d] bf16.
__global__ __launch_bounds__(256) void k_attention_mfma(const u16* __restrict__ qb,
                                                        const u16* __restrict__ kb,
                                                        const u16* __restrict__ vb,
                                                        const u16* __restrict__ krb,
                                                        u16* __restrict__ attn) {
    __shared__ __align__(16) u16 Klds[256 * 40];
    __shared__ __align__(16) u16 Vlds[32 * 264];
    __shared__ __align__(16) u16 KRlds[288 * 40];
    __shared__ __align__(16) u16 RPlds[32 * 290];
    __shared__ float smax[2][2][16];
    __shared__ float ssum[2][2][16];

    const int tid = threadIdx.x;
    const int t0 = blockIdx.x * 32;
    const int bh = blockIdx.y;
    const int b = bh >> 3, h = bh & 7;
    const int m_base = 224 - t0;

    const u16* kg  = kb  + (size_t)bh * 8192;
    const u16* vg  = vb  + (size_t)bh * 8192;
    const u16* krg = krb + m_base * 32;

    for (int i = tid; i < 1024; i += 256) {
        int s = i >> 2, c = i & 3;
        *(uint4*)&Klds[s * 40 + c * 8] = ((const uint4*)kg)[i];
    }
    for (int i = tid; i < 1024; i += 256) {
        int d = i >> 5, c = i & 31;
        *(uint4*)&Vlds[d * 264 + c * 8] = ((const uint4*)vg)[i];
    }
    for (int i = tid; i < 1152; i += 256) {
        int m = i >> 2, c = i & 3;
        *(uint4*)&KRlds[m * 40 + c * 8] = ((const uint4*)krg)[i];
    }

    const int wave = tid >> 6, lane = tid & 63;
    const int quad = lane >> 4, l15 = lane & 15;
    const int g = wave >> 1, half = wave & 1;

    s16x8 afrag = *(const s16x8*)(qb + (((size_t)bh * TT) + t0 + 16 * g + l15) * 32 + quad * 8);

    __syncthreads();

    // phase 1: R = Q x KR^T
    for (int nn = 0; nn < 9; ++nn) {
        int m0 = (half * 9 + nn) * 16;
        s16x8 bfrag = *(const s16x8*)&KRlds[(m0 + l15) * 40 + quad * 8];
        f32x4 c = {0.f, 0.f, 0.f, 0.f};
        c = __builtin_amdgcn_mfma_f32_16x16x32_bf16(afrag, bfrag, c, 0, 0, 0);
        int tl = 16 * g + quad * 4;
        int mcol = m0 + l15;
        RPlds[(tl + 0) * 290 + mcol] = f2bf(c[0]);
        RPlds[(tl + 1) * 290 + mcol] = f2bf(c[1]);
        RPlds[(tl + 2) * 290 + mcol] = f2bf(c[2]);
        RPlds[(tl + 3) * 290 + mcol] = f2bf(c[3]);
    }
    __syncthreads();

    // phase 2: S = Q K^T + gathered R, softmax
    f32x4 acc[8];
#pragma unroll
    for (int n = 0; n < 8; ++n) {
        int s0 = half * 128 + n * 16;
        s16x8 bfrag = *(const s16x8*)&Klds[(s0 + l15) * 40 + quad * 8];
        f32x4 z = {0.f, 0.f, 0.f, 0.f};
        acc[n] = __builtin_amdgcn_mfma_f32_16x16x32_bf16(afrag, bfrag, z, 0, 0, 0);
    }
#pragma unroll
    for (int n = 0; n < 8; ++n) {
        int s = half * 128 + n * 16 + l15;
#pragma unroll
        for (int r = 0; r < 4; ++r) {
            int tl = 16 * g + quad * 4 + r;
            acc[n][r] += bf2f(RPlds[tl * 290 + (s - tl + 31)]);
        }
    }
    float pm[4];
#pragma unroll
    for (int r = 0; r < 4; ++r) {
        float m = acc[0][r];
#pragma unroll
        for (int n = 1; n < 8; ++n) m = fmaxf(m, acc[n][r]);
#pragma unroll
        for (int off = 1; off < 16; off <<= 1) m = fmaxf(m, __shfl_xor(m, off, 64));
        pm[r] = m;
    }
    if (l15 == 0) {
#pragma unroll
        for (int r = 0; r < 4; ++r) smax[g][half][quad * 4 + r] = pm[r];
    }
    __syncthreads();
    float psum[4];
#pragma unroll
    for (int r = 0; r < 4; ++r) {
        float m = fmaxf(pm[r], smax[g][1 - half][quad * 4 + r]);
        float s = 0.f;
#pragma unroll
        for (int n = 0; n < 8; ++n) {
            float e = __expf(acc[n][r] - m);
            acc[n][r] = e;
            s += e;
        }
#pragma unroll
        for (int off = 1; off < 16; off <<= 1) s += __shfl_xor(s, off, 64);
        psum[r] = s;
    }
    if (l15 == 0) {
#pragma unroll
        for (int r = 0; r < 4; ++r) ssum[g][half][quad * 4 + r] = psum[r];
    }
    __syncthreads();
    float invr[4];
#pragma unroll
    for (int r = 0; r < 4; ++r)
        invr[r] = 1.f / (psum[r] + ssum[g][1 - half][quad * 4 + r]);
#pragma unroll
    for (int n = 0; n < 8; ++n) {
        int s = half * 128 + n * 16 + l15;
#pragma unroll
        for (int r = 0; r < 4; ++r) {
            int tl = 16 * g + quad * 4 + r;
            RPlds[tl * 264 + s] = f2bf(acc[n][r] * invr[r]);
        }
    }
    __syncthreads();

    // phase 3: O = P V^T -> attnT[b][t][c]
    f32x4 o = {0.f, 0.f, 0.f, 0.f};
#pragma unroll
    for (int ks = 0; ks < 8; ++ks) {
        s16x8 a  = *(const s16x8*)&RPlds[(16 * g + l15) * 264 + ks * 32 + quad * 8];
        s16x8 bv = *(const s16x8*)&Vlds[(half * 16 + l15) * 264 + ks * 32 + quad * 8];
        o = __builtin_amdgcn_mfma_f32_16x16x32_bf16(a, bv, o, 0, 0, 0);
    }
    int d = half * 16 + l15;
    int tb = t0 + 16 * g + quad * 4;
    u16* ob = attn + ((size_t)b * 256 + tb) * 256 + h * 32 + d;
    ob[0]   = f2bf(o[0]);
    ob[256] = f2bf(o[1]);
    ob[512] = f2bf(o[2]);
    ob[768] = f2bf(o[3]);
}

// ---------------------------------------------------------------------------
// K5: out[n][o][t][v] = relu((y[b=(n,v)][o][t] + x[n][o][t][v]) * inv[o] + shift[o])
__global__ __launch_bounds__(256) void k_final(const u16* __restrict__ y,
                                               const float* __restrict__ x,
                                               const float* __restrict__ gamma,
                                               const float* __restrict__ beta,
                                               const float* __restrict__ mean,
                                               const float* __restrict__ var,
                                               float* __restrict__ out) {
    __shared__ float tile[1600];
    const int tid = threadIdx.x;
    const int t0 = blockIdx.x * 64;
    const int o  = blockIdx.y;
    const int n  = blockIdx.z;
    float inv = gamma[o] * rsqrtf(var[o] + 1e-5f);
    float sh  = beta[o] - mean[o] * inv;
    for (int p = tid; p < 1600; p += 256) {
        int v = p >> 6, j = p & 63;
        tile[j * VV + v] = bf2f(y[(((size_t)(n * VV + v)) * CC + o) * TT + t0 + j]);
    }
    __syncthreads();
    size_t gbase = (((size_t)(n * CC + o)) * TT + t0) * VV;
    for (int i = tid; i < 1600; i += 256) {
        float val = tile[i] + x[gbase + i];
        val = val * inv + sh;
        out[gbase + i] = fmaxf(val, 0.f);
    }
}

// ---------------------------------------------------------------------------
extern "C" void kernel_launch(void* const* d_in, const int* in_sizes, int n_in,
                              void* d_out, int out_size, void* d_ws, size_t ws_size,
                              hipStream_t stream) {
    const float* x        = (const float*)d_in[0];
    const float* qkv_w    = (const float*)d_in[1];
    const float* qkv_b    = (const float*)d_in[2];
    const float* key_rel  = (const float*)d_in[3];
    const float* attn_w   = (const float*)d_in[4];
    const float* attn_b   = (const float*)d_in[5];
    const float* bn_gamma = (const float*)d_in[6];
    const float* bn_beta  = (const float*)d_in[7];
    const float* bn_mean  = (const float*)d_in[8];
    const float* bn_var   = (const float*)d_in[9];
    float* out = (float*)d_out;

    // d_ws: 5 x 26,214,400 = 131,072,000 bytes
    char* ws = (char*)d_ws;
    u16* xT    = (u16*)ws;
    u16* qT    = (u16*)(ws + 26214400);
    u16* kT    = (u16*)(ws + 52428800);
    u16* vb    = (u16*)(ws + 78643200);
    u16* attnT = (u16*)(ws + 104857600);
    u16* y     = qT;    // qT dead after attention; reuse for y

    // d_out doubles as scratch for packed weights (dead before k_final overwrites)
    char* outc = (char*)d_out;
    u16* Wqk   = (u16*)outc;                // 262,144 B
    u16* Wv    = (u16*)(outc + 262144);     // 131,072 B
    u16* Wo    = (u16*)(outc + 393216);     // 131,072 B
    float* bqk = (float*)(outc + 524288);   //   2,048 B
    u16* krb   = (u16*)(outc + 526336);     //  32,768 B

    k_pack_w<<<1026, 256, 0, stream>>>(qkv_w, attn_w, qkv_b, Wqk, Wv, Wo, bqk);
    k_pack_krel<<<64, 256, 0, stream>>>(key_rel, krb);
    k_transpose_x<<<dim3(8, 8, 8), 256, 0, stream>>>(x, xT);
    k_gemm_qk<<<dim3(4, 2, 200), 256, 0, stream>>>(xT, Wqk, bqk, qT, kT);
    k_gemm_av<<<dim3(2, 2, 200), 256, 0, stream>>>(Wv, qkv_b + 512, xT, vb);
    k_attention_mfma<<<dim3(8, 1600), 256, 0, stream>>>(qT, kT, vb, krb, attnT);
    k_gemm_av<<<dim3(2, 2, 200), 256, 0, stream>>>(Wo, attn_b, attnT, y);
    k_final<<<dim3(4, 256, 8), 256, 0, stream>>>(y, x, bn_gamma, bn_beta, bn_mean, bn_var, out);
}

// Round 4
// 345.584 us; speedup vs baseline: 5.7777x; 1.2455x over previous
//
#include <hip/hip_runtime.h>

#define NB 8
#define CC 256
#define TT 256
#define VV 25

typedef unsigned int u32;
typedef unsigned short u16;
typedef __attribute__((ext_vector_type(8))) short s16x8;
typedef __attribute__((ext_vector_type(4))) float f32x4;

__device__ __forceinline__ float bf2f(u16 u) { return __uint_as_float((u32)u << 16); }
__device__ __forceinline__ u16 f2bf(float f) {
    u32 u = __float_as_uint(f);
    u += 0x7fffu + ((u >> 16) & 1u);
    return (u16)(u >> 16);
}

__device__ __forceinline__ void gload_lds16(const void* g, void* l) {
    __builtin_amdgcn_global_load_lds(
        (const __attribute__((address_space(1))) u32*)g,
        (__attribute__((address_space(3))) u32*)l, 16, 0, 0);
}

// ---------------------------------------------------------------------------
// K1: x (N,C,T,V) f32 -> xT[b=(n*V+v)][t][c] bf16  (k-contiguous rows for MFMA A/B)
__global__ __launch_bounds__(256) void k_transpose_x(const float* __restrict__ x,
                                                     u16* __restrict__ xT) {
    __shared__ u16 L[25 * 32 * 34];
    const int tid = threadIdx.x;
    const int c0 = blockIdx.x * 32;
    const int t0 = blockIdx.y * 32;
    const int n  = blockIdx.z;
    for (int i = tid; i < 25600; i += 256) {
        int ci = i / 800;
        int rem = i - ci * 800;
        int t = rem / 25;
        int v = rem - t * 25;
        float f = x[(((size_t)(n * CC + c0 + ci)) * TT + t0) * VV + rem];
        L[(v * 32 + t) * 34 + ci] = f2bf(f);
    }
    __syncthreads();
    for (int i = tid; i < 12800; i += 256) {
        int row = i >> 4, cp = i & 15;
        int v = row >> 5, t = row & 31;
        u32 val = *(const u32*)&L[row * 34 + cp * 2];
        *(u32*)&xT[(((size_t)(n * VV + v)) * TT + t0 + t) * CC + c0 + cp * 2] = val;
    }
}

// ---------------------------------------------------------------------------
// K1b: key_rel (511,32) f32 -> krb[m][d] bf16, 512 rows (row 511 zeroed)
__global__ __launch_bounds__(256) void k_pack_krel(const float* __restrict__ kr,
                                                   u16* __restrict__ krb) {
    int g = blockIdx.x * 256 + threadIdx.x;
    if (g >= 16384) return;
    krb[g] = (g < 511 * 32) ? f2bf(kr[g]) : (u16)0;
}

// ---------------------------------------------------------------------------
// K1c: pack weights to bf16 (q rows pre-scaled by 1/sqrt(32)), scaled q bias
__global__ __launch_bounds__(256) void k_pack_w(const float* __restrict__ qkv_w,
                                                const float* __restrict__ attn_w,
                                                const float* __restrict__ qkv_b,
                                                u16* __restrict__ Wqk,
                                                u16* __restrict__ Wv,
                                                u16* __restrict__ Wo,
                                                float* __restrict__ bqk) {
    const float s = 0.17677669529663687f;
    int g = blockIdx.x * 256 + threadIdx.x;
    if (g < 131072) {
        Wqk[g] = f2bf(qkv_w[g] * (g < 65536 ? s : 1.f));
    } else if (g < 196608) {
        Wv[g - 131072] = f2bf(qkv_w[g]);             // qkv_w rows 512..767
    } else if (g < 262144) {
        Wo[g - 196608] = f2bf(attn_w[g - 196608]);
    } else if (g < 262656) {
        int i = g - 262144;
        bqk[i] = qkv_b[i] * (i < 256 ? s : 1.f);
    }
}

// ---------------------------------------------------------------------------
// m97-style mainloop: 128x128 tile, BK=32, async global->LDS, 4 waves x (4x4) 16x16 tiles.
__device__ __forceinline__ void gemm_mainloop(const u16* __restrict__ Arow,
                                              const u16* __restrict__ Brow,
                                              u16* At, u16* Bt,
                                              int wave, int lane, f32x4 acc[4][4]) {
    const int srow = lane >> 2, scol = (lane & 3) * 8;
    const int quad = lane >> 4, l15 = lane & 15;
    for (int k0 = 0; k0 < 256; k0 += 32) {
#pragma unroll
        for (int it = 0; it < 2; ++it) {
            int ch = it * 4 + wave;
            gload_lds16(Arow + (size_t)(ch * 16 + srow) * 256 + k0 + scol, At + ch * 512 + lane * 8);
            gload_lds16(Brow + (size_t)(ch * 16 + srow) * 256 + k0 + scol, Bt + ch * 512 + lane * 8);
        }
        __syncthreads();
        s16x8 af[4], bfr[4];
#pragma unroll
        for (int i = 0; i < 4; ++i)
            af[i] = *(const s16x8*)&At[((wave & 1) * 64 + i * 16 + l15) * 32 + quad * 8];
#pragma unroll
        for (int j = 0; j < 4; ++j)
            bfr[j] = *(const s16x8*)&Bt[((wave >> 1) * 64 + j * 16 + l15) * 32 + quad * 8];
#pragma unroll
        for (int i = 0; i < 4; ++i)
#pragma unroll
            for (int j = 0; j < 4; ++j)
                acc[i][j] = __builtin_amdgcn_mfma_f32_16x16x32_bf16(af[i], bfr[j], acc[i][j], 0, 0, 0);
        __syncthreads();
    }
}

// ---------------------------------------------------------------------------
// K2a: C[t][o] = xT . Wqk^T + bqk  -> qT[b][h][t][32], kT[b][h][s][32]
__global__ __launch_bounds__(256) void k_gemm_qk(const u16* __restrict__ xT,
                                                 const u16* __restrict__ Wqk,
                                                 const float* __restrict__ bqk,
                                                 u16* __restrict__ qT,
                                                 u16* __restrict__ kT) {
    __shared__ __align__(16) u16 At[128 * 32];
    __shared__ __align__(16) u16 Bt[128 * 32];
    const int tid = threadIdx.x, wave = tid >> 6, lane = tid & 63;
    const int quad = lane >> 4, l15 = lane & 15;
    const int n0 = blockIdx.x * 128;     // o
    const int m0 = blockIdx.y * 128;     // t
    const int b  = blockIdx.z;
    const u16* Arow = xT + (size_t)b * 65536 + (size_t)m0 * 256;
    const u16* Brow = Wqk + (size_t)n0 * 256;
    f32x4 acc[4][4];
#pragma unroll
    for (int i = 0; i < 4; ++i)
#pragma unroll
        for (int j = 0; j < 4; ++j) acc[i][j] = (f32x4){0.f, 0.f, 0.f, 0.f};
    gemm_mainloop(Arow, Brow, At, Bt, wave, lane, acc);

    const bool isq = (n0 < 256);
    u16* base = isq ? qT : kT;
    const int on0 = (isq ? n0 : n0 - 256) + (wave >> 1) * 64;
#pragma unroll
    for (int j = 0; j < 4; ++j) {
        int o = on0 + j * 16 + l15;
        float bias = bqk[(isq ? 0 : 256) + o];
        u16* dcol = base + (size_t)(b * 8 + (o >> 5)) * 8192 + (o & 31);
#pragma unroll
        for (int i = 0; i < 4; ++i) {
            int tbase = m0 + (wave & 1) * 64 + i * 16 + quad * 4;
#pragma unroll
            for (int r = 0; r < 4; ++r)
                dcol[(size_t)(tbase + r) * 32] = f2bf(acc[i][j][r] + bias);
        }
    }
}

// ---------------------------------------------------------------------------
// K2b (used twice): C[o][t] = W . Bsrc^T + bias -> Out[b][o][t]
__global__ __launch_bounds__(256) void k_gemm_av(const u16* __restrict__ Wb,
                                                 const float* __restrict__ bias,
                                                 const u16* __restrict__ Bsrc,
                                                 u16* __restrict__ Out) {
    __shared__ __align__(16) u16 At[128 * 32];
    __shared__ __align__(16) u16 Bt[128 * 32];
    const int tid = threadIdx.x, wave = tid >> 6, lane = tid & 63;
    const int quad = lane >> 4, l15 = lane & 15;
    const int n0 = blockIdx.x * 128;     // t
    const int m0 = blockIdx.y * 128;     // o
    const int b  = blockIdx.z;
    const u16* Arow = Wb + (size_t)m0 * 256;
    const u16* Brow = Bsrc + (size_t)b * 65536 + (size_t)n0 * 256;
    f32x4 acc[4][4];
#pragma unroll
    for (int i = 0; i < 4; ++i)
#pragma unroll
        for (int j = 0; j < 4; ++j) acc[i][j] = (f32x4){0.f, 0.f, 0.f, 0.f};
    gemm_mainloop(Arow, Brow, At, Bt, wave, lane, acc);

    u16* ob = Out + (size_t)b * 65536;
    const int nb = n0 + (wave >> 1) * 64 + l15;
#pragma unroll
    for (int i = 0; i < 4; ++i) {
        int o_i = m0 + (wave & 1) * 64 + i * 16 + quad * 4;
#pragma unroll
        for (int r = 0; r < 4; ++r) {
            float bv = bias[o_i + r];
            u16* orow = ob + (size_t)(o_i + r) * 256 + nb;
#pragma unroll
            for (int j = 0; j < 4; ++j)
                orow[j * 16] = f2bf(acc[i][j][r] + bv);
        }
    }
}

// ---------------------------------------------------------------------------
// K3: wave-autonomous MFMA attention. Each wave owns 16 t-rows end-to-end:
//   p1: R[16 x 272 band] = Q·KR^T (KR direct from global, L2-hot)
//   p2: S = Q·K^T (K direct from global) + gathered R, wave-local softmax
//   p3: O = P·V^T (P via wave-private LDS, V direct from global)
// Zero __syncthreads. LDS = 4 x 8.96KB wave-private R/P band (stride 280 u16:
// b128-aligned rows, all scalar patterns <=2-way on banks => free per m136).
// Grid (bh=1600, ttile=4): 1600%8==0 => all t-tiles of a bh on one XCD.
__global__ __launch_bounds__(256) void k_attention_mfma(const u16* __restrict__ qT,
                                                        const u16* __restrict__ kT,
                                                        const u16* __restrict__ vb,
                                                        const u16* __restrict__ krb,
                                                        u16* __restrict__ attn) {
    __shared__ __align__(16) u16 RP[4][16 * 280];

    const int tid = threadIdx.x;
    const int bh = blockIdx.x;
    const int b = bh >> 3, h = bh & 7;
    const int wave = tid >> 6, lane = tid & 63;
    const int quad = lane >> 4, l15 = lane & 15;
    const int t0w = blockIdx.y * 64 + wave * 16;    // this wave's first t-row
    const int tl = quad * 4;                        // C-layout row base (t-local)

    u16* rp = &RP[wave][0];
    const u16* qg  = qT  + (size_t)bh * 8192;
    const u16* kg  = kT  + (size_t)bh * 8192;
    const u16* vg  = vb  + (size_t)bh * 8192;
    const u16* krg = krb + (size_t)(240 - t0w) * 32;  // m = ml16 + 240 - t0w

    // A fragment: Q rows t0w..t0w+15, k-contiguous (1KB coalesced per wave)
    s16x8 afrag = *(const s16x8*)(qg + (size_t)(t0w + l15) * 32 + quad * 8);

    // ---- phase 1: R band (ml16 in [0,271], valid gathers use [0,270])
#pragma unroll
    for (int j = 0; j < 17; ++j) {
        s16x8 bfrag = *(const s16x8*)(krg + (size_t)(j * 16 + l15) * 32 + quad * 8);
        f32x4 c = {0.f, 0.f, 0.f, 0.f};
        c = __builtin_amdgcn_mfma_f32_16x16x32_bf16(afrag, bfrag, c, 0, 0, 0);
        int col = j * 16 + l15;
        rp[(tl + 0) * 280 + col] = f2bf(c[0]);
        rp[(tl + 1) * 280 + col] = f2bf(c[1]);
        rp[(tl + 2) * 280 + col] = f2bf(c[2]);
        rp[(tl + 3) * 280 + col] = f2bf(c[3]);
    }

    // ---- phase 2: S = Q K^T (full s range, 16 tiles)
    f32x4 acc[16];
#pragma unroll
    for (int n = 0; n < 16; ++n) {
        s16x8 kf = *(const s16x8*)(kg + (size_t)(n * 16 + l15) * 32 + quad * 8);
        f32x4 z = {0.f, 0.f, 0.f, 0.f};
        acc[n] = __builtin_amdgcn_mfma_f32_16x16x32_bf16(afrag, kf, z, 0, 0, 0);
    }
    // rel gather: S[t][s] += R[tlr][s - tlr + 15]
#pragma unroll
    for (int n = 0; n < 16; ++n) {
#pragma unroll
        for (int r = 0; r < 4; ++r) {
            int tlr = tl + r;
            acc[n][r] += bf2f(rp[tlr * 280 + (n * 16 + l15 - tlr + 15)]);
        }
    }
    // wave-local softmax: row = (quad,r), cols spread over n-regs x l15 lanes
    float invr[4];
#pragma unroll
    for (int r = 0; r < 4; ++r) {
        float m = acc[0][r];
#pragma unroll
        for (int n = 1; n < 16; ++n) m = fmaxf(m, acc[n][r]);
#pragma unroll
        for (int off = 1; off < 16; off <<= 1) m = fmaxf(m, __shfl_xor(m, off, 64));
        float s = 0.f;
#pragma unroll
        for (int n = 0; n < 16; ++n) {
            float e = __expf(acc[n][r] - m);
            acc[n][r] = e;
            s += e;
        }
#pragma unroll
        for (int off = 1; off < 16; off <<= 1) s += __shfl_xor(s, off, 64);
        invr[r] = 1.f / s;
    }
    // write P over the (dead) R band — wave-local ordering, no barrier
#pragma unroll
    for (int n = 0; n < 16; ++n) {
#pragma unroll
        for (int r = 0; r < 4; ++r)
            rp[(tl + r) * 280 + n * 16 + l15] = f2bf(acc[n][r] * invr[r]);
    }

    // ---- phase 3: O = P V^T (V direct from global; 2 d-tiles x 8 k-steps)
#pragma unroll
    for (int j = 0; j < 2; ++j) {
        f32x4 o = {0.f, 0.f, 0.f, 0.f};
#pragma unroll
        for (int ks = 0; ks < 8; ++ks) {
            s16x8 a  = *(const s16x8*)&rp[l15 * 280 + ks * 32 + quad * 8];
            s16x8 bv = *(const s16x8*)(vg + (size_t)(j * 16 + l15) * 256 + ks * 32 + quad * 8);
            o = __builtin_amdgcn_mfma_f32_16x16x32_bf16(a, bv, o, 0, 0, 0);
        }
        u16* ob = attn + ((size_t)b * 256 + t0w + tl) * 256 + h * 32 + j * 16 + l15;
        ob[0]   = f2bf(o[0]);
        ob[256] = f2bf(o[1]);
        ob[512] = f2bf(o[2]);
        ob[768] = f2bf(o[3]);
    }
}

// ---------------------------------------------------------------------------
// K5: out[n][o][t][v] = relu((y[b=(n,v)][o][t] + x[n][o][t][v]) * inv[o] + shift[o])
__global__ __launch_bounds__(256) void k_final(const u16* __restrict__ y,
                                               const float* __restrict__ x,
                                               const float* __restrict__ gamma,
                                               const float* __restrict__ beta,
                                               const float* __restrict__ mean,
                                               const float* __restrict__ var,
                                               float* __restrict__ out) {
    __shared__ float tile[1600];
    const int tid = threadIdx.x;
    const int t0 = blockIdx.x * 64;
    const int o  = blockIdx.y;
    const int n  = blockIdx.z;
    float inv = gamma[o] * rsqrtf(var[o] + 1e-5f);
    float sh  = beta[o] - mean[o] * inv;
    for (int p = tid; p < 1600; p += 256) {
        int v = p >> 6, j = p & 63;
        tile[j * VV + v] = bf2f(y[(((size_t)(n * VV + v)) * CC + o) * TT + t0 + j]);
    }
    __syncthreads();
    size_t gbase = (((size_t)(n * CC + o)) * TT + t0) * VV;
    for (int i = tid; i < 1600; i += 256) {
        float val = tile[i] + x[gbase + i];
        val = val * inv + sh;
        out[gbase + i] = fmaxf(val, 0.f);
    }
}

// ---------------------------------------------------------------------------
extern "C" void kernel_launch(void* const* d_in, const int* in_sizes, int n_in,
                              void* d_out, int out_size, void* d_ws, size_t ws_size,
                              hipStream_t stream) {
    const float* x        = (const float*)d_in[0];
    const float* qkv_w    = (const float*)d_in[1];
    const float* qkv_b    = (const float*)d_in[2];
    const float* key_rel  = (const float*)d_in[3];
    const float* attn_w   = (const float*)d_in[4];
    const float* attn_b   = (const float*)d_in[5];
    const float* bn_gamma = (const float*)d_in[6];
    const float* bn_beta  = (const float*)d_in[7];
    const float* bn_mean  = (const float*)d_in[8];
    const float* bn_var   = (const float*)d_in[9];
    float* out = (float*)d_out;

    // d_ws: 5 x 26,214,400 = 131,072,000 bytes
    char* ws = (char*)d_ws;
    u16* xT    = (u16*)ws;
    u16* qT    = (u16*)(ws + 26214400);
    u16* kT    = (u16*)(ws + 52428800);
    u16* vb    = (u16*)(ws + 78643200);
    u16* attnT = (u16*)(ws + 104857600);
    u16* y     = qT;    // qT dead after attention; reuse for y

    // d_out doubles as scratch for packed weights (dead before k_final overwrites)
    char* outc = (char*)d_out;
    u16* Wqk   = (u16*)outc;                // 262,144 B
    u16* Wv    = (u16*)(outc + 262144);     // 131,072 B
    u16* Wo    = (u16*)(outc + 393216);     // 131,072 B
    float* bqk = (float*)(outc + 524288);   //   2,048 B
    u16* krb   = (u16*)(outc + 526336);     //  32,768 B

    k_pack_w<<<1026, 256, 0, stream>>>(qkv_w, attn_w, qkv_b, Wqk, Wv, Wo, bqk);
    k_pack_krel<<<64, 256, 0, stream>>>(key_rel, krb);
    k_transpose_x<<<dim3(8, 8, 8), 256, 0, stream>>>(x, xT);
    k_gemm_qk<<<dim3(4, 2, 200), 256, 0, stream>>>(xT, Wqk, bqk, qT, kT);
    k_gemm_av<<<dim3(2, 2, 200), 256, 0, stream>>>(Wv, qkv_b + 512, xT, vb);
    k_attention_mfma<<<dim3(1600, 4), 256, 0, stream>>>(qT, kT, vb, krb, attnT);
    k_gemm_av<<<dim3(2, 2, 200), 256, 0, stream>>>(Wo, attn_b, attnT, y);
    k_final<<<dim3(4, 256, 8), 256, 0, stream>>>(y, x, bn_gamma, bn_beta, bn_mean, bn_var, out);
}